// Round 8
// baseline (335.151 us; speedup 1.0000x reference)
//
#include <hip/hip_runtime.h>
#include <hip/hip_bf16.h>
#include <stdint.h>

// ---------------------------------------------------------------------------
// MultiHeadAttention fused forward, MI355X (gfx950)
//   B=4, S=2048, D_MODEL=1024, H=16, depth=64; fp32 I/O, bf16 MFMA internal.
// R10 (GEMM: m201-style 256x256 8-phase schedule):
//   - gemm256_core: BM=BN=256, BK=64, 512 thr (2Mx4N waves, 128x64/wave,
//     acc[8][4]). 2-buf 128KB LDS. 8 phases / 2 K-tiles; per phase:
//     {12 ds_read_b128; 2 gload_lds; barrier; setprio(1); 16 MFMA;
//     setprio(0); [vmcnt(4) @ p4/p8]; barrier}. B stored nh-major in LDS so
//     every 64-row staging sweep has a known dead-phase; staging placement
//     derived so writes land after last read (barrier) and before first
//     read (vmcnt(4)). 128x64 wave tile => 12 ds_read per 32 MFMA (the
//     64x64 tile of R7 was LDS-read-bound at 16 reads per 32 MFMA).
//   - grid 128 blocks/plane (384 qkv, 128 dense), XCD-bijective swizzle.
//   - attn (R9 schedule) and flat cvt unchanged.
// ---------------------------------------------------------------------------

#define SEQ    2048
#define DEPTH  64
#define HEADS  16
#define NMODEL 1024
#define MROWS  8192   // B*S

typedef __bf16 bf16x8 __attribute__((ext_vector_type(8)));
typedef float  f32x4  __attribute__((ext_vector_type(4)));

#define MFMA16 __builtin_amdgcn_mfma_f32_16x16x32_bf16

__device__ __forceinline__ unsigned short f32_bf16(float f) {
    union { float f; unsigned int u; } c; c.f = f;
    unsigned int u = c.u + 0x7FFFu + ((c.u >> 16) & 1u);   // RNE
    return (unsigned short)(u >> 16);
}

__device__ __forceinline__ void gload16(const unsigned short* g, unsigned short* l) {
    __builtin_amdgcn_global_load_lds(
        (const __attribute__((address_space(1))) unsigned int*)g,
        (__attribute__((address_space(3))) unsigned int*)l, 16, 0, 0);
}

// ---------------------------------------------------------------------------
// All 7 fp32->bf16 conversions in one flat dispatch.
// Planes: 3 activations of 2^21 float4 each, then 4 weights of 2^18 each.
__global__ __launch_bounds__(256) void cvt_flat_kernel(
    const float* __restrict__ a0, const float* __restrict__ a1, const float* __restrict__ a2,
    const float* __restrict__ w0, const float* __restrict__ w1,
    const float* __restrict__ w2, const float* __restrict__ w3,
    unsigned short* __restrict__ oa0, unsigned short* __restrict__ oa1,
    unsigned short* __restrict__ oa2,
    unsigned short* __restrict__ ow0, unsigned short* __restrict__ ow1,
    unsigned short* __restrict__ ow2, unsigned short* __restrict__ ow3)
{
    const unsigned int i = blockIdx.x * 256u + threadIdx.x;
    const unsigned int NA = 1u << 21;          // float4 per activation
    const unsigned int AW = 3u * NA;           // activation region size
    const float* in; unsigned short* out; unsigned int idx;
    if (i < AW) {
        const unsigned int p = i >> 21; idx = i & (NA - 1u);
        in  = (p == 0) ? a0 : (p == 1) ? a1 : a2;
        out = (p == 0) ? oa0 : (p == 1) ? oa1 : oa2;
    } else {
        const unsigned int j = i - AW;
        const unsigned int p = j >> 18; idx = j & ((1u << 18) - 1u);
        in  = (p == 0) ? w0 : (p == 1) ? w1 : (p == 2) ? w2 : w3;
        out = (p == 0) ? ow0 : (p == 1) ? ow1 : (p == 2) ? ow2 : ow3;
    }
    float4 f = ((const float4*)in)[idx];
    ushort4 o;
    o.x = f32_bf16(f.x); o.y = f32_bf16(f.y);
    o.z = f32_bf16(f.z); o.w = f32_bf16(f.w);
    ((ushort4*)out)[idx] = o;
}

// ---------------------------------------------------------------------------
// 256x256 tile GEMM core, BK=64, XOR-swizzled LDS, 8 waves (2M x 4N),
// per-wave output 128x64 (acc[8][4]).  C[m,n] = sum_k A[m,k]*W[n,k]; K=1024.
//
// LDS: Abuf[2][256][64], Bbuf[2][256][64] bf16 (128 KB). Tile t -> buf t&1.
// B rows are stored nh-major: LDS row' = nh*128 + wc*32 + (j&1)*16 + l15
// (so each contiguous 64-row staging sweep is read only in nh-specific
// phases and has a known dead-phase).
//
// Phase order per tile: (mh,nh) = (0,0),(1,0),(0,1),(1,1).
// Region liveness (per tile, phases p1..p4 within its half-iteration):
//   B sweeps 0,1 (nh=0): read p1,p2  -> stage replacement at p3+
//   A sweeps 0,2 (mh=0): read p1,p3  -> stage at p4+
//   A sweeps 1,3 (mh=1): read p2,p4  -> stage at p5+
//   B sweeps 2,3 (nh=1): read p3,p4  -> stage at p5+
// Iteration i (tiles 2i in buf0 @ p1-4, 2i+1 in buf1 @ p5-8) stages:
//   p1: buf1.A1,A3 (tile 2i+1 late)   p2: buf1.B2,B3 (tile 2i+1 late)
//   p3: buf0.B0,B1 (tile 2i+2)        p4: buf0.A0,A2 (tile 2i+2) + vmcnt(4)
//   p5: buf0.A1,A3 (tile 2i+2)        p6: buf0.B2,B3 (tile 2i+2)
//   p7: buf1.B0,B1 (tile 2i+3)        p8: buf1.A0,A2 (tile 2i+3) + vmcnt(4)
// vmcnt(4) leaves exactly the last 2 phases' 4 loads in flight; everything
// needed by the next 4 phases is resident.
//
// mode 0: fp32 out row-major [.,NMODEL], bias[col]
// mode 1: bf16 out head-split [B,H,S,64], (acc+bias[col])*scale
// mode 2: bf16 out row-major [.,MROWS], bias[row]  (V^T), token order
//         permuted within 32-token groups: pi(k) = (k&3) + 4*((k>>4)&1)
//         + 8*((k>>2)&3)  -- matches attn's PV k-slot map.
__device__ __forceinline__ void gemm256_core(
    const unsigned short* __restrict__ A, const unsigned short* __restrict__ W,
    const float* __restrict__ bias, void* __restrict__ outp,
    int mode, float scale, int m0, int n0,
    unsigned short* __restrict__ Abuf, unsigned short* __restrict__ Bbuf)
{
    const int tid  = threadIdx.x;
    const int wave = tid >> 6, lane = tid & 63;
    const int l15  = lane & 15, quad = lane >> 4;
    const int wr   = wave >> 2, wc = wave & 3;   // 2 m-waves x 4 n-waves
    const int swz  = l15 & 7;
    const int K    = 1024;

    f32x4 acc[8][4] = {};

    // staging: thread tid covers row trow of each 64-row sweep, swizzled granule
    const int trow = tid >> 3;                       // 0..63
    const int tg   = ((tid & 7) ^ (trow & 7)) << 3;  // swizzled source granule
    const int dstw = wave * 512;                     // wave's 8-row slice in a sweep

    const unsigned short* Asw[4];
    const unsigned short* Bsw[4];
    #pragma unroll
    for (int sw = 0; sw < 4; ++sw) {
        Asw[sw] = A + (size_t)(m0 + sw * 64 + trow) * K + tg;
        // B sweep sw covers LDS rows' sw*64+trow; map row' -> global row
        const int rp  = sw * 64 + trow;
        const int nh  = rp >> 7, wcb = (rp >> 5) & 3, rem = rp & 31;
        Bsw[sw] = W + (size_t)(n0 + wcb * 64 + nh * 32 + rem) * K + tg;
    }

#define SA_(c, sw, kt) gload16(Asw[sw] + (kt) * 64, Abuf + (c) * 16384 + (sw) * 4096 + dstw)
#define SB_(c, sw, kt) gload16(Bsw[sw] + (kt) * 64, Bbuf + (c) * 16384 + (sw) * 4096 + dstw)

    // prologue: tile0 (all 8 sweeps) -> buf0; tile1 early (B0,B1,A0,A2) -> buf1
    SA_(0, 0, 0); SA_(0, 1, 0); SA_(0, 2, 0); SA_(0, 3, 0);
    SB_(0, 0, 0); SB_(0, 1, 0); SB_(0, 2, 0); SB_(0, 3, 0);
    SB_(1, 0, 1); SB_(1, 1, 1); SA_(1, 0, 1); SA_(1, 2, 1);
    asm volatile("s_waitcnt vmcnt(4)" ::: "memory");   // tile0 resident
    __builtin_amdgcn_s_barrier();

#define PHASE_(c, mh, nh, STG, DOVM) do {                                        \
    const unsigned short* Ab_ = Abuf + (c) * 16384;                              \
    const unsigned short* Bb_ = Bbuf + (c) * 16384;                              \
    bf16x8 a_[4][2], b_[2][2];                                                   \
    _Pragma("unroll")                                                            \
    for (int i4 = 0; i4 < 4; ++i4) {                                             \
        const int row = wr * 128 + ((mh) * 4 + i4) * 16 + l15;                   \
        a_[i4][0] = *(const bf16x8*)&Ab_[row * 64 + ((quad ^ swz) << 3)];        \
        a_[i4][1] = *(const bf16x8*)&Ab_[row * 64 + (((4 + quad) ^ swz) << 3)];  \
    }                                                                            \
    _Pragma("unroll")                                                            \
    for (int j2 = 0; j2 < 2; ++j2) {                                             \
        const int row = (nh) * 128 + wc * 32 + j2 * 16 + l15;                    \
        b_[j2][0] = *(const bf16x8*)&Bb_[row * 64 + ((quad ^ swz) << 3)];        \
        b_[j2][1] = *(const bf16x8*)&Bb_[row * 64 + (((4 + quad) ^ swz) << 3)];  \
    }                                                                            \
    STG;                                                                         \
    __builtin_amdgcn_s_barrier();                                                \
    __builtin_amdgcn_s_setprio(1);                                               \
    _Pragma("unroll")                                                            \
    for (int i4 = 0; i4 < 4; ++i4)                                               \
        _Pragma("unroll")                                                        \
        for (int j2 = 0; j2 < 2; ++j2) {                                         \
            acc[(mh)*4+i4][(nh)*2+j2] = MFMA16(a_[i4][0], b_[j2][0], acc[(mh)*4+i4][(nh)*2+j2], 0, 0, 0); \
            acc[(mh)*4+i4][(nh)*2+j2] = MFMA16(a_[i4][1], b_[j2][1], acc[(mh)*4+i4][(nh)*2+j2], 0, 0, 0); \
        }                                                                        \
    __builtin_amdgcn_s_setprio(0);                                               \
    if (DOVM) asm volatile("s_waitcnt vmcnt(4)" ::: "memory");                   \
    __builtin_amdgcn_s_barrier();                                                \
} while (0)

    for (int it = 0; it < 8; ++it) {
        const int t1 = 2 * it + 1, t2 = 2 * it + 2, t3 = 2 * it + 3;
        const bool h2 = t2 < 16, h3 = t3 < 16;
        PHASE_(0, 0, 0, { SA_(1, 1, t1); SA_(1, 3, t1); }, false);               // p1
        PHASE_(0, 1, 0, { SB_(1, 2, t1); SB_(1, 3, t1); }, false);               // p2
        PHASE_(0, 0, 1, { if (h2) { SB_(0, 0, t2); SB_(0, 1, t2); } }, false);   // p3
        PHASE_(0, 1, 1, { if (h2) { SA_(0, 0, t2); SA_(0, 2, t2); } }, true);    // p4
        PHASE_(1, 0, 0, { if (h2) { SA_(0, 1, t2); SA_(0, 3, t2); } }, false);   // p5
        PHASE_(1, 1, 0, { if (h2) { SB_(0, 2, t2); SB_(0, 3, t2); } }, false);   // p6
        PHASE_(1, 0, 1, { if (h3) { SB_(1, 0, t3); SB_(1, 1, t3); } }, false);   // p7
        PHASE_(1, 1, 1, { if (h3) { SA_(1, 0, t3); SA_(1, 2, t3); } }, it + 1 < 8); // p8
    }
#undef PHASE_
#undef SA_
#undef SB_

    #pragma unroll
    for (int i = 0; i < 8; ++i) {
        #pragma unroll
        for (int j = 0; j < 4; ++j) {
            const int col = n0 + wc * 64 + j * 16 + l15;
            const int row_b = m0 + wr * 128 + i * 16 + quad * 4;
            if (mode == 2) {
                // permuted token position within its 32-group
                const int colp = (col & ~31)
                               | (col & 3)
                               | (((col >> 4) & 1) << 2)
                               | (((col >> 2) & 3) << 3);
                #pragma unroll
                for (int r = 0; r < 4; ++r) {
                    const int row = row_b + r;
                    ((unsigned short*)outp)[(size_t)row * MROWS + colp] =
                        f32_bf16(acc[i][j][r] + bias[row]);
                }
            } else if (mode == 0) {
                const float bv = bias[col];
                #pragma unroll
                for (int r = 0; r < 4; ++r)
                    ((float*)outp)[(size_t)(row_b + r) * NMODEL + col] = acc[i][j][r] + bv;
            } else {
                const float bv = bias[col];
                const int h_ = col >> 6, d_ = col & 63;
                #pragma unroll
                for (int r = 0; r < 4; ++r) {
                    const int row = row_b + r;
                    const int b_ = row >> 11, s_ = row & 2047;
                    ((unsigned short*)outp)[(((size_t)(b_ * HEADS + h_) * SEQ + s_) << 6) + d_] =
                        f32_bf16((acc[i][j][r] + bv) * scale);
                }
            }
        }
    }
}

// QKV fused: grid (128, 3). z=0: Q (scaled), z=1: K, z=2: V^T (operands swapped)
__global__ __launch_bounds__(512, 2) void gemm_qkv(
    const unsigned short* __restrict__ qb,  const unsigned short* __restrict__ wqb,
    const float* __restrict__ bq, unsigned short* __restrict__ Qp,
    const unsigned short* __restrict__ kb,  const unsigned short* __restrict__ wkb,
    const float* __restrict__ bk, unsigned short* __restrict__ Kpj,
    const unsigned short* __restrict__ wvb, const unsigned short* __restrict__ vb,
    const float* __restrict__ bv, unsigned short* __restrict__ Vtg,
    float qscale)
{
    __shared__ unsigned short Abuf[2 * 16384];   // 64 KB
    __shared__ unsigned short Bbuf[2 * 16384];   // 64 KB
    const int o = blockIdx.x, z = blockIdx.y;
    const int sid = (o & 7) * 16 + (o >> 3);     // XCD-bijective (128 % 8 == 0)
    if (z == 0) {
        gemm256_core(qb, wqb, bq, Qp, 1, qscale, (sid >> 2) * 256, (sid & 3) * 256, Abuf, Bbuf);
    } else if (z == 1) {
        gemm256_core(kb, wkb, bk, Kpj, 1, 1.0f, (sid >> 2) * 256, (sid & 3) * 256, Abuf, Bbuf);
    } else {
        // M = 1024 (weights rows, 4 m-blocks), N = 8192 (activation rows, 32 n-blocks)
        gemm256_core(wvb, vb, bv, Vtg, 2, 1.0f, (sid & 3) * 256, (sid >> 2) * 256, Abuf, Bbuf);
    }
}

__global__ __launch_bounds__(512, 2) void gemm_dense(
    const unsigned short* __restrict__ A, const unsigned short* __restrict__ W,
    const float* __restrict__ bias, float* __restrict__ out)
{
    __shared__ unsigned short Abuf[2 * 16384];
    __shared__ unsigned short Bbuf[2 * 16384];
    const int o = blockIdx.x;
    const int sid = (o & 7) * 16 + (o >> 3);
    gemm256_core(A, W, bias, out, 0, 1.0f, (sid >> 2) * 256, (sid & 3) * 256, Abuf, Bbuf);
}

// ---------------------------------------------------------------------------
// Flash attention, S^T formulation, no-max softmax, register-resident P.
// Grid: (S/256, B*H). 4 waves; wave owns 64 q-rows. K-tiles of 64 keys.
// R9 schedule per tile: QK(both subtiles, 32-MFMA cluster) -> SM(0) ->
// [PV(0)+lacc cluster || SM(1)] -> PV(1)+lacc. 3-buf LDS, 2-deep prefetch,
// counted vmcnt(4), 1 barrier/tile. (Unchanged from R9.)
//
// PV k-slot map: slot s = quad*8+j of the PV MFMA for subtile `half` carries
//   key k = 32*half + 16*(j>>2) + 4*quad + (j&3)
// P B-fragment = lane's own S^T registers (no LDS, no shuffles).
// Vtg's global token order is pre-permuted (pi above) so the V A-fragment is
// ONE swizzled ds_read_b128 at granule (half*4+quad)^swz -- same pattern as K.
__global__ __launch_bounds__(256, 2) void attn_fwd(
    const unsigned short* __restrict__ Qp,   // [B,H,S,64] bf16, pre-scaled
    const unsigned short* __restrict__ Kp,   // [B,H,S,64] bf16
    const unsigned short* __restrict__ Vtg,  // [H*64, B*S] bf16, token-permuted
    unsigned short* __restrict__ Op)         // [B*S,1024] bf16
{
    __shared__ unsigned short Klds[3 * 64 * 64];
    __shared__ unsigned short Vlds[3 * 64 * 64];
    const int tid  = threadIdx.x;
    const int wave = tid >> 6, lane = tid & 63;
    const int l15  = lane & 15, quad = lane >> 4;
    const int swz  = l15 & 7;
    const int bh   = blockIdx.y;
    const int b_   = bh >> 4, h_ = bh & 15;
    const int q0   = blockIdx.x * 256;

    const unsigned short* Qb = Qp + (size_t)bh * SEQ * DEPTH;
    const unsigned short* Kb = Kp + (size_t)bh * SEQ * DEPTH;
    const unsigned short* Vb = Vtg + (size_t)h_ * DEPTH * MROWS + (size_t)b_ * SEQ;

    const int srow = (wave << 3) + (lane >> 3);
    const int scg  = (lane & 7) ^ ((lane >> 3) & 7);   // swizzled source granule

    const unsigned short* Kg0 = Kb + (size_t)srow * DEPTH + scg * 8;
    const unsigned short* Kg1 = Kb + (size_t)(srow + 32) * DEPTH + scg * 8;
    const unsigned short* Vg0 = Vb + (size_t)srow * MROWS + scg * 8;
    const unsigned short* Vg1 = Vb + (size_t)(srow + 32) * MROWS + scg * 8;

    // Q B-fragments (persistent): lane holds Q[q=16i+l15][d=32kc+quad*8+j]
    bf16x8 qf[4][2];
    #pragma unroll
    for (int i = 0; i < 4; ++i)
        #pragma unroll
        for (int kc = 0; kc < 2; ++kc)
            qf[i][kc] = *(const bf16x8*)(Qb + (size_t)(q0 + wave * 64 + i * 16 + l15) * DEPTH
                                         + kc * 32 + quad * 8);

    // all-ones bf16 A-fragment for the l-sum MFMA
    union { bf16x8 v; unsigned short s[8]; } uo;
    #pragma unroll
    for (int j = 0; j < 8; ++j) uo.s[j] = 0x3F80;
    const bf16x8 ones = uo.v;

    f32x4 Ot[4][4] = {};
    f32x4 lacc[4]  = {};

    auto STAGE = [&](int buf, int kt) {
        unsigned short* KW = &Klds[buf * 4096 + wave * 512];
        unsigned short* VW = &Vlds[buf * 4096 + wave * 512];
        gload16(Kg0 + (size_t)kt * 4096, KW);
        gload16(Kg1 + (size_t)kt * 4096, KW + 2048);
        gload16(Vg0 + kt * 64, VW);
        gload16(Vg1 + kt * 64, VW + 2048);
    };

    STAGE(0, 0);
    STAGE(1, 1);
    asm volatile("s_waitcnt vmcnt(4)" ::: "memory");   // tile0 resident, tile1 in flight
    __builtin_amdgcn_s_barrier();

    const int NT = SEQ / 64;   // 32
    for (int kt = 0; kt < NT; ++kt) {
        const unsigned short* Kc = &Klds[(kt % 3) * 4096];
        const unsigned short* Vc = &Vlds[(kt % 3) * 4096];
        if (kt + 2 < NT) STAGE((kt + 2) % 3, kt + 2);

        // ---- QK^T for BOTH 32-key subtiles: one 32-MFMA cluster ----
        f32x4 S[2][2][4];
        __builtin_amdgcn_s_setprio(1);
        #pragma unroll
        for (int half = 0; half < 2; ++half) {
            const int r0 = (2 * half) * 16 + l15;
            const int r1 = (2 * half + 1) * 16 + l15;
            bf16x8 ka0 = *(const bf16x8*)&Kc[r0 * 64 + ((quad ^ swz) << 3)];
            bf16x8 ka1 = *(const bf16x8*)&Kc[r0 * 64 + (((4 + quad) ^ swz) << 3)];
            bf16x8 kb0 = *(const bf16x8*)&Kc[r1 * 64 + ((quad ^ swz) << 3)];
            bf16x8 kb1 = *(const bf16x8*)&Kc[r1 * 64 + (((4 + quad) ^ swz) << 3)];
            #pragma unroll
            for (int i = 0; i < 4; ++i) {
                S[half][0][i] = f32x4{};
                S[half][0][i] = MFMA16(ka0, qf[i][0], S[half][0][i], 0, 0, 0);
                S[half][0][i] = MFMA16(ka1, qf[i][1], S[half][0][i], 0, 0, 0);
                S[half][1][i] = f32x4{};
                S[half][1][i] = MFMA16(kb0, qf[i][0], S[half][1][i], 0, 0, 0);
                S[half][1][i] = MFMA16(kb1, qf[i][1], S[half][1][i], 0, 0, 0);
            }
        }
        __builtin_amdgcn_s_setprio(0);

        // ---- SM(0): exp2 + pack subtile 0 ----
        bf16x8 pf0[4];
        #pragma unroll
        for (int i = 0; i < 4; ++i) {
            float e0 = __builtin_amdgcn_exp2f(S[0][0][i][0]);
            float e1 = __builtin_amdgcn_exp2f(S[0][0][i][1]);
            float e2 = __builtin_amdgcn_exp2f(S[0][0][i][2]);
            float e3 = __builtin_amdgcn_exp2f(S[0][0][i][3]);
            float e4 = __builtin_amdgcn_exp2f(S[0][1][i][0]);
            float e5 = __builtin_amdgcn_exp2f(S[0][1][i][1]);
            float e6 = __builtin_amdgcn_exp2f(S[0][1][i][2]);
            float e7 = __builtin_amdgcn_exp2f(S[0][1][i][3]);
            union { bf16x8 v; __hip_bfloat162 h[4]; } up;
            up.h[0] = __float22bfloat162_rn(make_float2(e0, e1));
            up.h[1] = __float22bfloat162_rn(make_float2(e2, e3));
            up.h[2] = __float22bfloat162_rn(make_float2(e4, e5));
            up.h[3] = __float22bfloat162_rn(make_float2(e6, e7));
            pf0[i] = up.v;
        }

        // ---- PV(0)+lacc cluster; SM(1) below has no dep and overlaps ----
        __builtin_amdgcn_s_setprio(1);
        lacc[0] = MFMA16(ones, pf0[0], lacc[0], 0, 0, 0);
        lacc[1] = MFMA16(ones, pf0[1], lacc[1], 0, 0, 0);
        lacc[2] = MFMA16(ones, pf0[2], lacc[2], 0, 0, 0);
        lacc[3] = MFMA16(ones, pf0[3], lacc[3], 0, 0, 0);
        #pragma unroll
        for (int dd = 0; dd < 4; ++dd) {
            bf16x8 vf = *(const bf16x8*)&Vc[(dd * 16 + l15) * 64 + ((quad ^ swz) << 3)];
            #pragma unroll
            for (int i = 0; i < 4; ++i)
                Ot[i][dd] = MFMA16(vf, pf0[i], Ot[i][dd], 0, 0, 0);
        }
        __builtin_amdgcn_s_setprio(0);

        // ---- SM(1): exp2 + pack subtile 1 (overlaps PV(0) above) ----
        bf16x8 pf1[4];
        #pragma unroll
        for (int i = 0; i < 4; ++i) {
            float e0 = __builtin_amdgcn_exp2f(S[1][0][i][0]);
            float e1 = __builtin_amdgcn_exp2f(S[1][0][i][1]);
            float e2 = __builtin_amdgcn_exp2f(S[1][0][i][2]);
            float e3 = __builtin_amdgcn_exp2f(S[1][0][i][3]);
            float e4 = __builtin_amdgcn_exp2f(S[1][1][i][0]);
            float e5 = __builtin_amdgcn_exp2f(S[1][1][i][1]);
            float e6 = __builtin_amdgcn_exp2f(S[1][1][i][2]);
            float e7 = __builtin_amdgcn_exp2f(S[1][1][i][3]);
            union { bf16x8 v; __hip_bfloat162 h[4]; } up;
            up.h[0] = __float22bfloat162_rn(make_float2(e0, e1));
            up.h[1] = __float22bfloat162_rn(make_float2(e2, e3));
            up.h[2] = __float22bfloat162_rn(make_float2(e4, e5));
            up.h[3] = __float22bfloat162_rn(make_float2(e6, e7));
            pf1[i] = up.v;
        }

        // ---- PV(1)+lacc cluster ----
        __builtin_amdgcn_s_setprio(1);
        lacc[0] = MFMA16(ones, pf1[0], lacc[0], 0, 0, 0);
        lacc[1] = MFMA16(ones, pf1[1], lacc[1], 0, 0, 0);
        lacc[2] = MFMA16(ones, pf1[2], lacc[2], 0, 0, 0);
        lacc[3] = MFMA16(ones, pf1[3], lacc[3], 0, 0, 0);
        #pragma unroll
        for (int dd = 0; dd < 4; ++dd) {
            bf16x8 vf = *(const bf16x8*)&Vc[(dd * 16 + l15) * 64 + (((4 + quad) ^ swz) << 3)];
            #pragma unroll
            for (int i = 0; i < 4; ++i)
                Ot[i][dd] = MFMA16(vf, pf1[i], Ot[i][dd], 0, 0, 0);
        }
        __builtin_amdgcn_s_setprio(0);

        // counted hand-off: tile kt+1 resident; kt+2's loads stay in flight
        if (kt + 2 < NT)
            asm volatile("s_waitcnt vmcnt(4)" ::: "memory");
        else
            asm volatile("s_waitcnt vmcnt(0)" ::: "memory");
        __builtin_amdgcn_s_barrier();
    }

    // lacc[i][*] already holds the full denominator for q = i*16+l15
    #pragma unroll
    for (int i = 0; i < 4; ++i) {
        const float inv = 1.0f / lacc[i][0];
        const int row = b_ * SEQ + q0 + wave * 64 + i * 16 + l15;
        #pragma unroll
        for (int dd = 0; dd < 4; ++dd) {
            ushort4 ov;
            ov.x = f32_bf16(Ot[i][dd][0] * inv);
            ov.y = f32_bf16(Ot[i][dd][1] * inv);
            ov.z = f32_bf16(Ot[i][dd][2] * inv);
            ov.w = f32_bf16(Ot[i][dd][3] * inv);
            const int col = h_ * 64 + dd * 16 + quad * 4;
            *(ushort4*)&Op[(size_t)row * NMODEL + col] = ov;
        }
    }
}

// ---------------------------------------------------------------------------
extern "C" void kernel_launch(void* const* d_in, const int* in_sizes, int n_in,
                              void* d_out, int out_size, void* d_ws, size_t ws_size,
                              hipStream_t stream) {
    const float* q  = (const float*)d_in[0];
    const float* k  = (const float*)d_in[1];
    const float* v  = (const float*)d_in[2];
    const float* wq = (const float*)d_in[3];
    const float* bq = (const float*)d_in[4];
    const float* wk = (const float*)d_in[5];
    const float* bk = (const float*)d_in[6];
    const float* wv = (const float*)d_in[7];
    const float* bv = (const float*)d_in[8];
    const float* wd = (const float*)d_in[9];
    const float* bd = (const float*)d_in[10];

    char* ws = (char*)d_ws;
    size_t off = 0;
    auto alloc = [&](size_t bytes) { char* p = ws + off; off += bytes; return p; };
    const size_t ACT = (size_t)MROWS * NMODEL * 2;
    const size_t WGT = (size_t)NMODEL * NMODEL * 2;

    unsigned short* qb   = (unsigned short*)alloc(ACT);
    unsigned short* kb   = (unsigned short*)alloc(ACT);
    unsigned short* vb   = (unsigned short*)alloc(ACT);
    unsigned short* wqb  = (unsigned short*)alloc(WGT);
    unsigned short* wkb  = (unsigned short*)alloc(WGT);
    unsigned short* wvb  = (unsigned short*)alloc(WGT);
    unsigned short* wdb  = (unsigned short*)alloc(WGT);
    unsigned short* Qp   = (unsigned short*)alloc(ACT);
    unsigned short* Kpj  = (unsigned short*)alloc(ACT);
    unsigned short* Vtg  = (unsigned short*)alloc(ACT);   // [H*64, B*S], token-permuted
    unsigned short* attn = (unsigned short*)alloc(ACT);

    // 3*2^21 + 4*2^18 = 7,340,032 float4 -> 28,672 blocks
    cvt_flat_kernel<<<28672, 256, 0, stream>>>(
        q, k, v, wq, wk, wv, wd, qb, kb, vb, wqb, wkb, wvb, wdb);

    const float SC = 0.18033688011112042f;   // log2(e)/sqrt(64)
    gemm_qkv<<<dim3(128, 3), 512, 0, stream>>>(qb, wqb, bq, Qp,
                                               kb, wkb, bk, Kpj,
                                               wvb, vb, bv, Vtg, SC);

    attn_fwd<<<dim3(SEQ / 256, 64), 256, 0, stream>>>(Qp, Kpj, Vtg, attn);

    gemm_dense<<<128, 512, 0, stream>>>(attn, wdb, bd, (float*)d_out);
}

// Round 9
// 315.368 us; speedup vs baseline: 1.0627x; 1.0627x over previous
//
#include <hip/hip_runtime.h>
#include <hip/hip_bf16.h>
#include <stdint.h>

// ---------------------------------------------------------------------------
// MultiHeadAttention fused forward, MI355X (gfx950)
//   B=4, S=2048, D_MODEL=1024, H=16, depth=64; fp32 I/O, bf16 MFMA internal.
// R11:
//   - GEMM: reverted to R7's gemm256_core (256x128, BK=64, 3-buf LDS 144KB,
//     2-deep prefetch, counted vmcnt(6), 1 barrier/tile, 256 blocks/plane)
//     -- the measured-best GEMM (315 us total). R10's 256x256 8-phase port
//     regressed (12 ds_read per 16 MFMA vs R7's 16 per 32) and is dropped.
//   - attn: 8 waves x 32 q-rows (512 threads), 2-buf 32KB LDS ->
//     16 waves/CU = 4 waves/SIMD (was 2). R8/R9 showed attn is neither
//     staging- nor order-bound; pipes all <30% busy => latency-bound with
//     too few contexts. Doubling TLP is the remaining lever. Same verified
//     math: V-permutation, register P, ones-MFMA l-sum, R9 cluster order.
//   - flat cvt unchanged.
// ---------------------------------------------------------------------------

#define SEQ    2048
#define DEPTH  64
#define HEADS  16
#define NMODEL 1024
#define MROWS  8192   // B*S

typedef __bf16 bf16x8 __attribute__((ext_vector_type(8)));
typedef float  f32x4  __attribute__((ext_vector_type(4)));

#define MFMA16 __builtin_amdgcn_mfma_f32_16x16x32_bf16

__device__ __forceinline__ unsigned short f32_bf16(float f) {
    union { float f; unsigned int u; } c; c.f = f;
    unsigned int u = c.u + 0x7FFFu + ((c.u >> 16) & 1u);   // RNE
    return (unsigned short)(u >> 16);
}

__device__ __forceinline__ void gload16(const unsigned short* g, unsigned short* l) {
    __builtin_amdgcn_global_load_lds(
        (const __attribute__((address_space(1))) unsigned int*)g,
        (__attribute__((address_space(3))) unsigned int*)l, 16, 0, 0);
}

// ---------------------------------------------------------------------------
// All 7 fp32->bf16 conversions in one flat dispatch.
// Planes: 3 activations of 2^21 float4 each, then 4 weights of 2^18 each.
__global__ __launch_bounds__(256) void cvt_flat_kernel(
    const float* __restrict__ a0, const float* __restrict__ a1, const float* __restrict__ a2,
    const float* __restrict__ w0, const float* __restrict__ w1,
    const float* __restrict__ w2, const float* __restrict__ w3,
    unsigned short* __restrict__ oa0, unsigned short* __restrict__ oa1,
    unsigned short* __restrict__ oa2,
    unsigned short* __restrict__ ow0, unsigned short* __restrict__ ow1,
    unsigned short* __restrict__ ow2, unsigned short* __restrict__ ow3)
{
    const unsigned int i = blockIdx.x * 256u + threadIdx.x;
    const unsigned int NA = 1u << 21;          // float4 per activation
    const unsigned int AW = 3u * NA;           // activation region size
    const float* in; unsigned short* out; unsigned int idx;
    if (i < AW) {
        const unsigned int p = i >> 21; idx = i & (NA - 1u);
        in  = (p == 0) ? a0 : (p == 1) ? a1 : a2;
        out = (p == 0) ? oa0 : (p == 1) ? oa1 : oa2;
    } else {
        const unsigned int j = i - AW;
        const unsigned int p = j >> 18; idx = j & ((1u << 18) - 1u);
        in  = (p == 0) ? w0 : (p == 1) ? w1 : (p == 2) ? w2 : w3;
        out = (p == 0) ? ow0 : (p == 1) ? ow1 : (p == 2) ? ow2 : ow3;
    }
    float4 f = ((const float4*)in)[idx];
    ushort4 o;
    o.x = f32_bf16(f.x); o.y = f32_bf16(f.y);
    o.z = f32_bf16(f.z); o.w = f32_bf16(f.w);
    ((ushort4*)out)[idx] = o;
}

// ---------------------------------------------------------------------------
// 256x128 tile GEMM core, BK=64, XOR-swizzled LDS, 8 waves (4M x 2N).
// C[m,n] = sum_k A[m,k]*W[n,k]; K = 1024 (16 K-tiles).
// Pipeline: 3 LDS buffers, 2-deep prefetch, counted vmcnt(6), 1 barrier/tile.
// mode 0: fp32 out row-major [.,NMODEL], bias[col]
// mode 1: bf16 out head-split [B,H,S,64], (acc+bias[col])*scale
// mode 2: bf16 out row-major [.,MROWS], bias[row]   (V^T), token order
//         permuted within 32-token groups: pi(k) = (k&3) + 4*((k>>4)&1)
//         + 8*((k>>2)&3)  -- matches attn's PV k-slot map.
__device__ __forceinline__ void gemm256_core(
    const unsigned short* __restrict__ A, const unsigned short* __restrict__ W,
    const float* __restrict__ bias, void* __restrict__ outp,
    int mode, float scale, int m0, int n0,
    unsigned short* __restrict__ Alds, unsigned short* __restrict__ Blds)
{
    const int tid  = threadIdx.x;
    const int wave = tid >> 6, lane = tid & 63;
    const int l15  = lane & 15, quad = lane >> 4;
    const int wr   = wave >> 1, wc = wave & 1;   // 4 m-waves x 2 n-waves
    const int swz  = l15 & 7;
    const int K    = 1024;

    f32x4 acc[4][4] = {};

    // staging: thread tid covers row trow of each 64-row sweep, swizzled granule
    const int trow = tid >> 3;                       // 0..63
    const int tg   = ((tid & 7) ^ (trow & 7)) << 3;  // swizzled source granule (shorts)
    const unsigned short* Asrc[2][2];                // [unit u][sweep s]
    const unsigned short* Bsrc[2];
    #pragma unroll
    for (int u = 0; u < 2; ++u) {
        #pragma unroll
        for (int s = 0; s < 2; ++s)
            Asrc[u][s] = A + (size_t)(m0 + u * 128 + s * 64 + trow) * K + tg;
        Bsrc[u] = W + (size_t)(n0 + u * 64 + trow) * K + tg;
    }

    // stage K-tile kt2 into buffer buf: 6 global_load_lds per lane
    auto STAGE = [&](int buf, int kt2) {
        unsigned short* Ad = Alds + buf * 16384;
        unsigned short* Bd = Blds + buf * 8192;
        gload16(Asrc[0][0] + kt2 * 64, Ad + (      wave * 8) * 64);
        gload16(Asrc[0][1] + kt2 * 64, Ad + ( 64 + wave * 8) * 64);
        gload16(Asrc[1][0] + kt2 * 64, Ad + (128 + wave * 8) * 64);
        gload16(Asrc[1][1] + kt2 * 64, Ad + (192 + wave * 8) * 64);
        gload16(Bsrc[0]    + kt2 * 64, Bd + (      wave * 8) * 64);
        gload16(Bsrc[1]    + kt2 * 64, Bd + ( 64 + wave * 8) * 64);
    };

    STAGE(0, 0);
    STAGE(1, 1);
    asm volatile("s_waitcnt vmcnt(6)" ::: "memory");   // tile0 resident, tile1 in flight
    __builtin_amdgcn_s_barrier();

    const int arow = wr * 64 + l15;
    const int brow = wc * 64 + l15;

    for (int kt = 0; kt < 16; ++kt) {
        const unsigned short* Ab = Alds + (kt % 3) * 16384;
        const unsigned short* Bb = Blds + (kt % 3) * 8192;

        // kc=0 fragments
        bf16x8 a0[4], b0[4];
        {
            const int pg = ((quad ^ swz) << 3);
            #pragma unroll
            for (int j = 0; j < 4; ++j)
                b0[j] = *(const bf16x8*)&Bb[(brow + j * 16) * 64 + pg];
            #pragma unroll
            for (int i = 0; i < 4; ++i)
                a0[i] = *(const bf16x8*)&Ab[(arow + i * 16) * 64 + pg];
        }
        // issue next-next tile's loads under this tile's compute
        if (kt + 2 < 16) STAGE((kt + 2) % 3, kt + 2);

        __builtin_amdgcn_s_setprio(1);
        #pragma unroll
        for (int i = 0; i < 4; ++i)
            #pragma unroll
            for (int j = 0; j < 4; ++j)
                acc[i][j] = MFMA16(a0[i], b0[j], acc[i][j], 0, 0, 0);
        __builtin_amdgcn_s_setprio(0);

        // kc=1 fragments (reads overlap the kc=0 MFMA cluster above)
        bf16x8 a1[4], b1[4];
        {
            const int pg = (((4 + quad) ^ swz) << 3);
            #pragma unroll
            for (int j = 0; j < 4; ++j)
                b1[j] = *(const bf16x8*)&Bb[(brow + j * 16) * 64 + pg];
            #pragma unroll
            for (int i = 0; i < 4; ++i)
                a1[i] = *(const bf16x8*)&Ab[(arow + i * 16) * 64 + pg];
        }
        __builtin_amdgcn_s_setprio(1);
        #pragma unroll
        for (int i = 0; i < 4; ++i)
            #pragma unroll
            for (int j = 0; j < 4; ++j)
                acc[i][j] = MFMA16(a1[i], b1[j], acc[i][j], 0, 0, 0);
        __builtin_amdgcn_s_setprio(0);

        // counted hand-off: next tile's 6 loads must be done; keep 6 in flight
        if (kt + 2 < 16)
            asm volatile("s_waitcnt vmcnt(6)" ::: "memory");
        else
            asm volatile("s_waitcnt vmcnt(0)" ::: "memory");
        __builtin_amdgcn_s_barrier();
    }

    #pragma unroll
    for (int i = 0; i < 4; ++i) {
        #pragma unroll
        for (int j = 0; j < 4; ++j) {
            const int col = n0 + wc * 64 + j * 16 + l15;
            const int row_b = m0 + wr * 64 + i * 16 + quad * 4;
            if (mode == 2) {
                // permuted token position within its 32-group
                const int colp = (col & ~31)
                               | (col & 3)
                               | (((col >> 4) & 1) << 2)
                               | (((col >> 2) & 3) << 3);
                #pragma unroll
                for (int r = 0; r < 4; ++r) {
                    const int row = row_b + r;
                    ((unsigned short*)outp)[(size_t)row * MROWS + colp] =
                        f32_bf16(acc[i][j][r] + bias[row]);
                }
            } else if (mode == 0) {
                const float bv = bias[col];
                #pragma unroll
                for (int r = 0; r < 4; ++r)
                    ((float*)outp)[(size_t)(row_b + r) * NMODEL + col] = acc[i][j][r] + bv;
            } else {
                const float bv = bias[col];
                const int h_ = col >> 6, d_ = col & 63;
                #pragma unroll
                for (int r = 0; r < 4; ++r) {
                    const int row = row_b + r;
                    const int b_ = row >> 11, s_ = row & 2047;
                    ((unsigned short*)outp)[(((size_t)(b_ * HEADS + h_) * SEQ + s_) << 6) + d_] =
                        f32_bf16((acc[i][j][r] + bv) * scale);
                }
            }
        }
    }
}

// QKV fused: grid (256, 3). z=0: Q (scaled), z=1: K, z=2: V^T (operands swapped)
__global__ __launch_bounds__(512, 2) void gemm_qkv(
    const unsigned short* __restrict__ qb,  const unsigned short* __restrict__ wqb,
    const float* __restrict__ bq, unsigned short* __restrict__ Qp,
    const unsigned short* __restrict__ kb,  const unsigned short* __restrict__ wkb,
    const float* __restrict__ bk, unsigned short* __restrict__ Kpj,
    const unsigned short* __restrict__ wvb, const unsigned short* __restrict__ vb,
    const float* __restrict__ bv, unsigned short* __restrict__ Vtg,
    float qscale)
{
    __shared__ unsigned short Alds[3 * 256 * 64];   // 96 KB
    __shared__ unsigned short Blds[3 * 128 * 64];   // 48 KB
    const int o = blockIdx.x, z = blockIdx.y;
    const int sid = (o & 7) * 32 + (o >> 3);        // XCD-bijective swizzle (256%8==0)
    if (z == 0) {
        gemm256_core(qb, wqb, bq, Qp, 1, qscale, (sid >> 3) * 256, (sid & 7) * 128, Alds, Blds);
    } else if (z == 1) {
        gemm256_core(kb, wkb, bk, Kpj, 1, 1.0f, (sid >> 3) * 256, (sid & 7) * 128, Alds, Blds);
    } else {
        // M = 1024 (weights rows, 4 m-blocks), N = 8192 (activation rows, 64 n-blocks)
        gemm256_core(wvb, vb, bv, Vtg, 2, 1.0f, (sid & 3) * 256, (sid >> 2) * 128, Alds, Blds);
    }
}

__global__ __launch_bounds__(512, 2) void gemm_dense(
    const unsigned short* __restrict__ A, const unsigned short* __restrict__ W,
    const float* __restrict__ bias, float* __restrict__ out)
{
    __shared__ unsigned short Alds[3 * 256 * 64];
    __shared__ unsigned short Blds[3 * 128 * 64];
    const int o = blockIdx.x;
    const int sid = (o & 7) * 32 + (o >> 3);
    gemm256_core(A, W, bias, out, 0, 1.0f, (sid >> 3) * 256, (sid & 7) * 128, Alds, Blds);
}

// ---------------------------------------------------------------------------
// Flash attention, S^T formulation, no-max softmax, register-resident P.
// R11: 512 threads, 8 waves x 32 q-rows (block = 256 q-rows), 2-buf 32KB LDS
// -> 2 blocks/CU = 16 waves/CU = 4 waves/SIMD (double the TLP of the 4-wave
// version). Grid (S/256, B*H) = (8, 64). K-tiles of 64 keys.
// Per-tile schedule (R9 order): QK(16-MFMA cluster, both subtiles) -> SM(0)
// -> [PV(0)+lacc || SM(1)] -> PV(1)+lacc. Staging: 2 gload16/thread/tile.
//
// PV k-slot map: slot s = quad*8+j of the PV MFMA for subtile `half` carries
//   key k = 32*half + 16*(j>>2) + 4*quad + (j&3)
// P B-fragment = lane's own S^T registers (no LDS, no shuffles).
// Vtg's global token order is pre-permuted (pi in gemm mode 2) so the V
// A-fragment is ONE swizzled ds_read_b128 -- same proven pattern as K.
__global__ __launch_bounds__(512, 2) void attn_fwd(
    const unsigned short* __restrict__ Qp,   // [B,H,S,64] bf16, pre-scaled
    const unsigned short* __restrict__ Kp,   // [B,H,S,64] bf16
    const unsigned short* __restrict__ Vtg,  // [H*64, B*S] bf16, token-permuted
    unsigned short* __restrict__ Op)         // [B*S,1024] bf16
{
    __shared__ unsigned short Klds[2 * 64 * 64];   // 16 KB
    __shared__ unsigned short Vlds[2 * 64 * 64];   // 16 KB
    const int tid  = threadIdx.x;
    const int wave = tid >> 6, lane = tid & 63;    // wave 0..7
    const int l15  = lane & 15, quad = lane >> 4;
    const int swz  = l15 & 7;
    const int bh   = blockIdx.y;
    const int b_   = bh >> 4, h_ = bh & 15;
    const int q0   = blockIdx.x * 256;

    const unsigned short* Qb = Qp + (size_t)bh * SEQ * DEPTH;
    const unsigned short* Kb = Kp + (size_t)bh * SEQ * DEPTH;
    const unsigned short* Vb = Vtg + (size_t)h_ * DEPTH * MROWS + (size_t)b_ * SEQ;

    // staging: 512 threads cover one 64x64 tile with ONE gload16 each.
    // thread covers row srow (0..63), swizzled source granule scg.
    const int srow = tid >> 3;
    const int scg  = (tid & 7) ^ (srow & 7);
    const unsigned short* Kgp = Kb + (size_t)srow * DEPTH + scg * 8;   // +kt*4096
    const unsigned short* Vgp = Vb + (size_t)srow * MROWS + scg * 8;   // +kt*64
    // LDS dest: wave w writes rows 8w..8w+7 linearly (gload_lds semantics)
    const int dstw = wave * 512;

    // Q B-fragments (persistent): lane holds Q[q=16i+l15][d=32kc+quad*8+j]
    bf16x8 qf[2][2];
    #pragma unroll
    for (int i = 0; i < 2; ++i)
        #pragma unroll
        for (int kc = 0; kc < 2; ++kc)
            qf[i][kc] = *(const bf16x8*)(Qb + (size_t)(q0 + wave * 32 + i * 16 + l15) * DEPTH
                                         + kc * 32 + quad * 8);

    // all-ones bf16 A-fragment for the l-sum MFMA
    union { bf16x8 v; unsigned short s[8]; } uo;
    #pragma unroll
    for (int j = 0; j < 8; ++j) uo.s[j] = 0x3F80;
    const bf16x8 ones = uo.v;

    f32x4 Ot[2][4] = {};
    f32x4 lacc[2]  = {};

    auto STAGE = [&](int buf, int kt) {
        gload16(Kgp + (size_t)kt * 4096, &Klds[buf * 4096 + dstw]);
        gload16(Vgp + kt * 64,           &Vlds[buf * 4096 + dstw]);
    };

    STAGE(0, 0);
    asm volatile("s_waitcnt vmcnt(0)" ::: "memory");
    __builtin_amdgcn_s_barrier();

    const int NT = SEQ / 64;   // 32
    for (int kt = 0; kt < NT; ++kt) {
        const int cur = kt & 1;
        // issue next tile's loads; buffer cur^1 was last read in kt-1 whose
        // end-of-iteration barrier precedes this issue (race-free).
        if (kt + 1 < NT) STAGE(cur ^ 1, kt + 1);

        const unsigned short* Kc = &Klds[cur * 4096];
        const unsigned short* Vc = &Vlds[cur * 4096];

        // ---- QK^T for BOTH 32-key subtiles: one 16-MFMA cluster ----
        f32x4 S[2][2][2];   // [half][key-row s][m-frag i]
        __builtin_amdgcn_s_setprio(1);
        #pragma unroll
        for (int half = 0; half < 2; ++half) {
            const int r0 = (2 * half) * 16 + l15;
            const int r1 = (2 * half + 1) * 16 + l15;
            bf16x8 ka0 = *(const bf16x8*)&Kc[r0 * 64 + ((quad ^ swz) << 3)];
            bf16x8 ka1 = *(const bf16x8*)&Kc[r0 * 64 + (((4 + quad) ^ swz) << 3)];
            bf16x8 kb0 = *(const bf16x8*)&Kc[r1 * 64 + ((quad ^ swz) << 3)];
            bf16x8 kb1 = *(const bf16x8*)&Kc[r1 * 64 + (((4 + quad) ^ swz) << 3)];
            #pragma unroll
            for (int i = 0; i < 2; ++i) {
                S[half][0][i] = f32x4{};
                S[half][0][i] = MFMA16(ka0, qf[i][0], S[half][0][i], 0, 0, 0);
                S[half][0][i] = MFMA16(ka1, qf[i][1], S[half][0][i], 0, 0, 0);
                S[half][1][i] = f32x4{};
                S[half][1][i] = MFMA16(kb0, qf[i][0], S[half][1][i], 0, 0, 0);
                S[half][1][i] = MFMA16(kb1, qf[i][1], S[half][1][i], 0, 0, 0);
            }
        }
        __builtin_amdgcn_s_setprio(0);

        // ---- SM(0): exp2 + pack subtile 0 ----
        bf16x8 pf0[2];
        #pragma unroll
        for (int i = 0; i < 2; ++i) {
            float e0 = __builtin_amdgcn_exp2f(S[0][0][i][0]);
            float e1 = __builtin_amdgcn_exp2f(S[0][0][i][1]);
            float e2 = __builtin_amdgcn_exp2f(S[0][0][i][2]);
            float e3 = __builtin_amdgcn_exp2f(S[0][0][i][3]);
            float e4 = __builtin_amdgcn_exp2f(S[0][1][i][0]);
            float e5 = __builtin_amdgcn_exp2f(S[0][1][i][1]);
            float e6 = __builtin_amdgcn_exp2f(S[0][1][i][2]);
            float e7 = __builtin_amdgcn_exp2f(S[0][1][i][3]);
            union { bf16x8 v; __hip_bfloat162 h[4]; } up;
            up.h[0] = __float22bfloat162_rn(make_float2(e0, e1));
            up.h[1] = __float22bfloat162_rn(make_float2(e2, e3));
            up.h[2] = __float22bfloat162_rn(make_float2(e4, e5));
            up.h[3] = __float22bfloat162_rn(make_float2(e6, e7));
            pf0[i] = up.v;
        }

        // ---- PV(0)+lacc cluster; SM(1) below has no dep and overlaps ----
        __builtin_amdgcn_s_setprio(1);
        lacc[0] = MFMA16(ones, pf0[0], lacc[0], 0, 0, 0);
        lacc[1] = MFMA16(ones, pf0[1], lacc[1], 0, 0, 0);
        #pragma unroll
        for (int dd = 0; dd < 4; ++dd) {
            bf16x8 vf = *(const bf16x8*)&Vc[(dd * 16 + l15) * 64 + ((quad ^ swz) << 3)];
            Ot[0][dd] = MFMA16(vf, pf0[0], Ot[0][dd], 0, 0, 0);
            Ot[1][dd] = MFMA16(vf, pf0[1], Ot[1][dd], 0, 0, 0);
        }
        __builtin_amdgcn_s_setprio(0);

        // ---- SM(1): exp2 + pack subtile 1 (overlaps PV(0) above) ----
        bf16x8 pf1[2];
        #pragma unroll
        for (int i = 0; i < 2; ++i) {
            float e0 = __builtin_amdgcn_exp2f(S[1][0][i][0]);
            float e1 = __builtin_amdgcn_exp2f(S[1][0][i][1]);
            float e2 = __builtin_amdgcn_exp2f(S[1][0][i][2]);
            float e3 = __builtin_amdgcn_exp2f(S[1][0][i][3]);
            float e4 = __builtin_amdgcn_exp2f(S[1][1][i][0]);
            float e5 = __builtin_amdgcn_exp2f(S[1][1][i][1]);
            float e6 = __builtin_amdgcn_exp2f(S[1][1][i][2]);
            float e7 = __builtin_amdgcn_exp2f(S[1][1][i][3]);
            union { bf16x8 v; __hip_bfloat162 h[4]; } up;
            up.h[0] = __float22bfloat162_rn(make_float2(e0, e1));
            up.h[1] = __float22bfloat162_rn(make_float2(e2, e3));
            up.h[2] = __float22bfloat162_rn(make_float2(e4, e5));
            up.h[3] = __float22bfloat162_rn(make_float2(e6, e7));
            pf1[i] = up.v;
        }

        // ---- PV(1)+lacc cluster ----
        __builtin_amdgcn_s_setprio(1);
        lacc[0] = MFMA16(ones, pf1[0], lacc[0], 0, 0, 0);
        lacc[1] = MFMA16(ones, pf1[1], lacc[1], 0, 0, 0);
        #pragma unroll
        for (int dd = 0; dd < 4; ++dd) {
            bf16x8 vf = *(const bf16x8*)&Vc[(dd * 16 + l15) * 64 + (((4 + quad) ^ swz) << 3)];
            Ot[0][dd] = MFMA16(vf, pf1[0], Ot[0][dd], 0, 0, 0);
            Ot[1][dd] = MFMA16(vf, pf1[1], Ot[1][dd], 0, 0, 0);
        }
        __builtin_amdgcn_s_setprio(0);

        // drain this iteration's prefetch before the buffer-swap barrier
        asm volatile("s_waitcnt vmcnt(0)" ::: "memory");
        __builtin_amdgcn_s_barrier();
    }

    // lacc[i][*] already holds the full denominator for q = i*16+l15
    #pragma unroll
    for (int i = 0; i < 2; ++i) {
        const float inv = 1.0f / lacc[i][0];
        const int row = b_ * SEQ + q0 + wave * 32 + i * 16 + l15;
        #pragma unroll
        for (int dd = 0; dd < 4; ++dd) {
            ushort4 ov;
            ov.x = f32_bf16(Ot[i][dd][0] * inv);
            ov.y = f32_bf16(Ot[i][dd][1] * inv);
            ov.z = f32_bf16(Ot[i][dd][2] * inv);
            ov.w = f32_bf16(Ot[i][dd][3] * inv);
            const int col = h_ * 64 + dd * 16 + quad * 4;
            *(ushort4*)&Op[(size_t)row * NMODEL + col] = ov;
        }
    }
}

// ---------------------------------------------------------------------------
extern "C" void kernel_launch(void* const* d_in, const int* in_sizes, int n_in,
                              void* d_out, int out_size, void* d_ws, size_t ws_size,
                              hipStream_t stream) {
    const float* q  = (const float*)d_in[0];
    const float* k  = (const float*)d_in[1];
    const float* v  = (const float*)d_in[2];
    const float* wq = (const float*)d_in[3];
    const float* bq = (const float*)d_in[4];
    const float* wk = (const float*)d_in[5];
    const float* bk = (const float*)d_in[6];
    const float* wv = (const float*)d_in[7];
    const float* bv = (const float*)d_in[8];
    const float* wd = (const float*)d_in[9];
    const float* bd = (const float*)d_in[10];

    char* ws = (char*)d_ws;
    size_t off = 0;
    auto alloc = [&](size_t bytes) { char* p = ws + off; off += bytes; return p; };
    const size_t ACT = (size_t)MROWS * NMODEL * 2;
    const size_t WGT = (size_t)NMODEL * NMODEL * 2;

    unsigned short* qb   = (unsigned short*)alloc(ACT);
    unsigned short* kb   = (unsigned short*)alloc(ACT);
    unsigned short* vb   = (unsigned short*)alloc(ACT);
    unsigned short* wqb  = (unsigned short*)alloc(WGT);
    unsigned short* wkb  = (unsigned short*)alloc(WGT);
    unsigned short* wvb  = (unsigned short*)alloc(WGT);
    unsigned short* wdb  = (unsigned short*)alloc(WGT);
    unsigned short* Qp   = (unsigned short*)alloc(ACT);
    unsigned short* Kpj  = (unsigned short*)alloc(ACT);
    unsigned short* Vtg  = (unsigned short*)alloc(ACT);   // [H*64, B*S], token-permuted
    unsigned short* attn = (unsigned short*)alloc(ACT);

    // 3*2^21 + 4*2^18 = 7,340,032 float4 -> 28,672 blocks
    cvt_flat_kernel<<<28672, 256, 0, stream>>>(
        q, k, v, wq, wk, wv, wd, qb, kb, vb, wqb, wkb, wvb, wdb);

    const float SC = 0.18033688011112042f;   // log2(e)/sqrt(64)
    gemm_qkv<<<dim3(256, 3), 512, 0, stream>>>(qb, wqb, bq, Qp,
                                               kb, wkb, bk, Kpj,
                                               wvb, vb, bv, Vtg, SC);

    attn_fwd<<<dim3(SEQ / 256, 64), 512, 0, stream>>>(Qp, Kpj, Vtg, attn);

    gemm_dense<<<256, 512, 0, stream>>>(attn, wdb, bd, (float*)d_out);
}